// Round 11
// baseline (491.205 us; speedup 1.0000x reference)
//
#include <hip/hip_runtime.h>
#include <hip/hip_bf16.h>

// Problem constants: B=4, N=4096, C=256, h=8, d=32, M=512, EPS=1e-5
#define SCALE_QK 0.17677669529663687f  // 32^-0.5

typedef __attribute__((ext_vector_type(8))) short bf16x8;
typedef __attribute__((ext_vector_type(4))) float f32x4;

__device__ __forceinline__ unsigned short bf16_rne(float v) {
  const unsigned int b = __float_as_uint(v);
  const unsigned int r = b + 0x7FFFu + ((b >> 16) & 1u);
  return (unsigned short)(r >> 16);
}
__device__ __forceinline__ float bf16_f32(unsigned short h) {
  return __uint_as_float(((unsigned int)h) << 16);
}

// ---------------------------------------------------------------------------
// prep: transpose weights + zero ssq/sumv
// ---------------------------------------------------------------------------
__global__ __launch_bounds__(256) void prep_kernel(
    const float* __restrict__ pw, const float* __restrict__ kvw,
    const float* __restrict__ pjw,
    float* __restrict__ wtpw, float* __restrict__ wtkv, float* __restrict__ wtpj,
    float* __restrict__ ssq, float* __restrict__ sumv) {
  const int g = blockIdx.x * 256 + threadIdx.x;
  if (g < 65536) {
    const int c = g >> 8, o = g & 255;
    wtpw[g] = pw[o * 256 + c];
  } else if (g < 196608) {
    const int g2 = g - 65536;
    const int c = g2 >> 9, o = g2 & 511;
    wtkv[g2] = kvw[o * 256 + c];
  } else {
    const int g3 = g - 196608;
    const int c = g3 >> 8, o = g3 & 255;
    wtpj[g3] = pjw[o * 256 + c];
  }
  if (g < 512) ssq[g] = 0.0f;
  if (g >= 512 && g < 512 + 1024) sumv[g - 512] = 0.0f;
}

// ---------------------------------------------------------------------------
// depthwise conv3d + BatchNorm -> qdw[B,N,C]
// ---------------------------------------------------------------------------
__global__ __launch_bounds__(256) void dwbn_kernel(
    const float* __restrict__ x, const float* __restrict__ w,
    const float* __restrict__ wb, const float* __restrict__ bg,
    const float* __restrict__ bb, const float* __restrict__ bm,
    const float* __restrict__ bv, float* __restrict__ outq) {
  const int blk = blockIdx.x;
  const int b = blk >> 12, n = blk & 4095;
  const int i0 = n >> 8, i1 = (n >> 4) & 15, i2 = n & 15;
  const int c = threadIdx.x;
  float acc = wb[c];
#pragma unroll
  for (int k0 = 0; k0 < 3; ++k0) {
    const int z = i0 + k0 - 1;
    if ((unsigned)z >= 16u) continue;
#pragma unroll
    for (int k1 = 0; k1 < 3; ++k1) {
      const int y = i1 + k1 - 1;
      if ((unsigned)y >= 16u) continue;
#pragma unroll
      for (int k2 = 0; k2 < 3; ++k2) {
        const int xx = i2 + k2 - 1;
        if ((unsigned)xx >= 16u) continue;
        acc = fmaf(w[c * 27 + (k0 * 3 + k1) * 3 + k2],
                   x[((b * 4096) + ((z * 16 + y) * 16 + xx)) * 256 + c], acc);
      }
    }
  }
  const float sc = bg[c] * rsqrtf(bv[c] + 1e-5f);
  outq[blk * 256 + c] = (acc - bm[c]) * sc + bb[c];
}

// ---------------------------------------------------------------------------
// strided depthwise conv3d + LayerNorm -> xsln[B*M, C]
// ---------------------------------------------------------------------------
__global__ __launch_bounds__(256) void srln_kernel(
    const float* __restrict__ x, const float* __restrict__ w,
    const float* __restrict__ wb, const float* __restrict__ lg,
    const float* __restrict__ lb, float* __restrict__ outx) {
  const int blk = blockIdx.x;
  const int b = blk >> 9, m = blk & 511;
  const int o0 = m >> 6, o1 = (m >> 3) & 7, o2 = m & 7;
  const int c = threadIdx.x;
  float acc = wb[c];
#pragma unroll
  for (int k0 = 0; k0 < 3; ++k0) {
    const int z = o0 * 2 + k0 - 1;
    if ((unsigned)z >= 16u) continue;
#pragma unroll
    for (int k1 = 0; k1 < 3; ++k1) {
      const int y = o1 * 2 + k1 - 1;
      if ((unsigned)y >= 16u) continue;
#pragma unroll
      for (int k2 = 0; k2 < 3; ++k2) {
        const int xx = o2 * 2 + k2 - 1;
        if ((unsigned)xx >= 16u) continue;
        acc = fmaf(w[c * 27 + (k0 * 3 + k1) * 3 + k2],
                   x[((b * 4096) + ((z * 16 + y) * 16 + xx)) * 256 + c], acc);
      }
    }
  }
  __shared__ float r1[4], r2[4];
  float s1 = acc, s2 = acc * acc;
#pragma unroll
  for (int off = 32; off >= 1; off >>= 1) {
    s1 += __shfl_xor(s1, off);
    s2 += __shfl_xor(s2, off);
  }
  const int t = threadIdx.x;
  if ((t & 63) == 0) { r1[t >> 6] = s1; r2[t >> 6] = s2; }
  __syncthreads();
  const float mu = (r1[0] + r1[1] + r1[2] + r1[3]) * (1.0f / 256.0f);
  const float ms = (r2[0] + r2[1] + r2[2] + r2[3]) * (1.0f / 256.0f);
  const float rs = rsqrtf(ms - mu * mu + 1e-5f);
  outx[blk * 256 + c] = (acc - mu) * rs * lg[c] + lb[c];
}

// ---------------------------------------------------------------------------
// GEMM v2: 64 rows x 128 cols per block. MODE 1: deferred instance-norm on A.
// ---------------------------------------------------------------------------
template <int MODE>
__global__ __launch_bounds__(256) void gemm_kernel(
    const float* __restrict__ A, const float* __restrict__ Wt,
    const float* __restrict__ bias, float* __restrict__ Out, const int ldW,
    const float* __restrict__ sumv, const float* __restrict__ rstd) {
  __shared__ float a_t[32][68];
  __shared__ float w_s[32][132];
  const int t = threadIdx.x;
  const int r0 = blockIdx.x * 64;
  const int c0 = blockIdx.y * 128;
  const int rt = t & 15, ct = t >> 4;
  const int bidx = r0 >> 12;
  const float invM = 1.0f / 512.0f;
  float acc[4][8];
#pragma unroll
  for (int rr = 0; rr < 4; ++rr)
#pragma unroll
    for (int cc = 0; cc < 8; ++cc) acc[rr][cc] = 0.0f;

  for (int k0 = 0; k0 < 256; k0 += 32) {
    {
      const int kk = t & 31;
      int rl = t >> 5;
#pragma unroll
      for (int p = 0; p < 8; ++p, rl += 8) {
        float v = A[(r0 + rl) * 256 + k0 + kk];
        if (MODE == 1) {
          const int kg = k0 + kk;
          v = (v - invM * sumv[bidx * 256 + kg]) * rstd[bidx * 8 + (kg >> 5)];
        }
        a_t[kk][rl] = v;
      }
    }
    {
      const int cq = (t & 31) * 4;
      int kk = t >> 5;
#pragma unroll
      for (int p = 0; p < 4; ++p, kk += 8) {
        const float4 v = *(const float4*)&Wt[(k0 + kk) * ldW + c0 + cq];
        *(float4*)&w_s[kk][cq] = v;
      }
    }
    __syncthreads();
#pragma unroll
    for (int kk = 0; kk < 32; ++kk) {
      const float4 a4 = *(const float4*)&a_t[kk][rt * 4];
      const float av[4] = {a4.x, a4.y, a4.z, a4.w};
      float4 w4[2];
#pragma unroll
      for (int q = 0; q < 2; ++q) w4[q] = *(const float4*)&w_s[kk][ct * 8 + q * 4];
#pragma unroll
      for (int rr = 0; rr < 4; ++rr) {
#pragma unroll
        for (int q = 0; q < 2; ++q) {
          acc[rr][q * 4 + 0] = fmaf(av[rr], w4[q].x, acc[rr][q * 4 + 0]);
          acc[rr][q * 4 + 1] = fmaf(av[rr], w4[q].y, acc[rr][q * 4 + 1]);
          acc[rr][q * 4 + 2] = fmaf(av[rr], w4[q].z, acc[rr][q * 4 + 2]);
          acc[rr][q * 4 + 3] = fmaf(av[rr], w4[q].w, acc[rr][q * 4 + 3]);
        }
      }
    }
    __syncthreads();
  }
#pragma unroll
  for (int rr = 0; rr < 4; ++rr) {
    const int row = r0 + rt * 4 + rr;
#pragma unroll
    for (int q = 0; q < 2; ++q) {
      const int cc = c0 + ct * 8 + q * 4;
      float4 o;
      o.x = acc[rr][q * 4 + 0];
      o.y = acc[rr][q * 4 + 1];
      o.z = acc[rr][q * 4 + 2];
      o.w = acc[rr][q * 4 + 3];
      if (bias != nullptr) {
        o.x += bias[cc + 0]; o.y += bias[cc + 1];
        o.z += bias[cc + 2]; o.w += bias[cc + 3];
      }
      *(float4*)&Out[row * ldW + cc] = o;
    }
  }
}

// ---------------------------------------------------------------------------
// kt v2: K^T -> bf16 hi/lo packed in MFMA B-frag order:
// kthl[b][kt8=k>>3][m][s][e=k&7] ushort; b128-loadable per lane.
// ---------------------------------------------------------------------------
__global__ __launch_bounds__(256) void kt_kernel(const float* __restrict__ kvb,
                                                 unsigned short* __restrict__ kthl) {
  __shared__ float tile[32][33];
  const int blk = blockIdx.x;  // b(4) x mt(16) x k8(8)
  const int b = blk >> 7, mt = (blk >> 3) & 15, k8 = blk & 7;
  const int m0 = mt * 32, k0 = k8 * 32;
  const int t = threadIdx.x;
  {
    const int ml = t >> 3, kl = (t & 7) * 4;
    const float4 v = *(const float4*)&kvb[((b * 512 + m0 + ml) * 512) + k0 + kl];
    tile[ml][kl + 0] = v.x; tile[ml][kl + 1] = v.y;
    tile[ml][kl + 2] = v.z; tile[ml][kl + 3] = v.w;
  }
  __syncthreads();
  {
    const int s = t >> 7, kt8l = (t >> 5) & 3, mloc = t & 31;
    unsigned int pk[4];
#pragma unroll
    for (int ep = 0; ep < 4; ++ep) {
      unsigned short h0, h1;
      {
        const float v = tile[mloc][kt8l * 8 + ep * 2];
        const unsigned short hi = bf16_rne(v);
        h0 = (s == 0) ? hi : bf16_rne(v - bf16_f32(hi));
      }
      {
        const float v = tile[mloc][kt8l * 8 + ep * 2 + 1];
        const unsigned short hi = bf16_rne(v);
        h1 = (s == 0) ? hi : bf16_rne(v - bf16_f32(hi));
      }
      pk[ep] = (unsigned int)h0 | ((unsigned int)h1 << 16);
    }
    const int kt8 = k8 * 4 + kt8l;
    uint4 u;
    u.x = pk[0]; u.y = pk[1]; u.z = pk[2]; u.w = pk[3];
    *(uint4*)&kthl[((((size_t)b * 32 + kt8) * 512 + (m0 + mloc)) * 2 + s) * 8] = u;
  }
}

// ---------------------------------------------------------------------------
// sumv[b][c] = sum_m v[b][m][c]
// ---------------------------------------------------------------------------
__global__ __launch_bounds__(256) void sumv_kernel(const float* __restrict__ kvb,
                                                   float* __restrict__ sumv) {
  const int blk = blockIdx.x;
  const int b = blk >> 3, grp = blk & 7;
  const int c = threadIdx.x;
  float s = 0.0f;
  for (int mm = 0; mm < 64; ++mm) {
    const int m = grp * 64 + mm;
    s += kvb[((b * 512 + m) * 512) + 256 + c];
  }
  atomicAdd(&sumv[b * 256 + c], s);
}

__global__ void rstd_kernel(const float* __restrict__ ssq, float* __restrict__ rstd) {
  const int t = threadIdx.x;
  if (t < 32) {
    float s = 0.0f;
#pragma unroll
    for (int sp = 0; sp < 16; ++sp) s += ssq[sp * 32 + t];
    const float e2 = s * (1.0f / (4096.0f * 512.0f));
    const float invM = 1.0f / 512.0f;
    rstd[t] = rsqrtf(e2 - invM * invM + 1e-5f);
  }
}

// ---------------------------------------------------------------------------
// Fused attention v9: block = (b, 8 q-rows), 512 thr. QK+mix as ONE MFMA GEMM:
// Mixed[64 rows=(i,r)][512 m] = A[64][256] x K^T, A[(i,r)][c] =
// W[i][c>>5]*q[r][c]*scale, split bf16 hi/lo (3 mfma -> ~fp32 accuracy).
// A staged in frag layout in LDS (aliased with P). Softmax on C-frags
// (16-lane shfl + 2-level LDS combine). PV = verified v8 fp32 path.
// ---------------------------------------------------------------------------
__device__ __forceinline__ int pswz2(int row, int m) {
  const int q = m >> 2;
  const int qs = q ^ ((q >> 3) & 7);
  return row * 512 + (qs << 2) + (m & 3);
}

__global__ __launch_bounds__(512, 4) void attn_kernel(
    const float* __restrict__ qb, const unsigned short* __restrict__ kthl,
    const float* __restrict__ kvb, const float* __restrict__ tw,
    float* __restrict__ ssq, float* __restrict__ out_un) {
  __shared__ float P[16384];       // 64KB: A-frags (QK) -> p / partials (PV)
  __shared__ float red[64][8][2];  // wave-local max/expsum
  __shared__ float red2[64][2];    // global MX, 1/S per row
  __shared__ float sq_lds[64][8];
  const int t = threadIdx.x, blk = blockIdx.x;
  const int b = blk >> 9, n0 = (blk & 511) << 3;
  const int w = t >> 6, l = t & 63;
  const int l15 = l & 15, l4 = l >> 4;
  unsigned short* Au = (unsigned short*)P;  // [mt4][kt8][s2][lane64][e8]

  // ---- stage A (q * W * scale, hi/lo) into frag layout ----
  {
    const int r = t >> 6, c4 = (t & 63) * 4;
    const float4 q4 = *(const float4*)&qb[((b * 4096 + n0 + r) * 256) + c4];
    const float qv[4] = {q4.x, q4.y, q4.z, q4.w};
    const int kt = c4 >> 5;  // constant over c4..c4+3
#pragma unroll
    for (int i = 0; i < 8; ++i) {
      const float wij = tw[i * 8 + kt] * SCALE_QK;
      const int mt = i >> 1;
      const int rowin = (i & 1) * 8 + r;
#pragma unroll
      for (int cc = 0; cc < 4; ++cc) {
        const int c = c4 + cc;
        const float v = qv[cc] * wij;
        const unsigned short hi = bf16_rne(v);
        const unsigned short lo = bf16_rne(v - bf16_f32(hi));
        const int lane = rowin | (((c & 31) >> 3) << 4);
        const int idx = (((mt * 8 + kt) * 2) * 64 + lane) * 8 + (c & 7);
        Au[idx] = hi;
        Au[idx + 512] = lo;  // s=1 plane
      }
    }
  }
  __syncthreads();

  // ---- QK mfma: wave w owns m in [w*64, w*64+64) (4 tiles of 16) ----
  f32x4 C[4][4];  // [mt][t]
#pragma unroll
  for (int mt = 0; mt < 4; ++mt)
#pragma unroll
    for (int tt = 0; tt < 4; ++tt) C[mt][tt] = (f32x4){0.f, 0.f, 0.f, 0.f};

#pragma unroll
  for (int kt = 0; kt < 8; ++kt) {
#pragma unroll
    for (int th = 0; th < 2; ++th) {
      bf16x8 Bh[2], Bl[2];
#pragma unroll
      for (int tp = 0; tp < 2; ++tp) {
        const int m = w * 64 + (th * 2 + tp) * 16 + l15;
        const size_t bi = ((((size_t)b * 32 + kt * 4 + l4) * 512 + m) * 2) * 8;
        Bh[tp] = *(const bf16x8*)&kthl[bi];
        Bl[tp] = *(const bf16x8*)&kthl[bi + 8];
      }
#pragma unroll
      for (int mt = 0; mt < 4; ++mt) {
        const int ab = (((mt * 8 + kt) * 2) * 64 + l) * 8;
        const bf16x8 Ah = *(const bf16x8*)&Au[ab];
        const bf16x8 Al = *(const bf16x8*)&Au[ab + 512];
#pragma unroll
        for (int tp = 0; tp < 2; ++tp) {
          const int ti = th * 2 + tp;
          C[mt][ti] = __builtin_amdgcn_mfma_f32_16x16x32_bf16(Ah, Bh[tp], C[mt][ti], 0, 0, 0);
          C[mt][ti] = __builtin_amdgcn_mfma_f32_16x16x32_bf16(Ah, Bl[tp], C[mt][ti], 0, 0, 0);
          C[mt][ti] = __builtin_amdgcn_mfma_f32_16x16x32_bf16(Al, Bh[tp], C[mt][ti], 0, 0, 0);
        }
      }
    }
  }

  // ---- softmax pass 1 (wave-local, 16-lane row groups) ----
  float mxloc[4][4];
#pragma unroll
  for (int mt = 0; mt < 4; ++mt) {
#pragma unroll
    for (int rg = 0; rg < 4; ++rg) {
      float mx = fmaxf(fmaxf(C[mt][0][rg], C[mt][1][rg]),
                       fmaxf(C[mt][2][rg], C[mt][3][rg]));
      mx = fmaxf(mx, __shfl_xor(mx, 1));
      mx = fmaxf(mx, __shfl_xor(mx, 2));
      mx = fmaxf(mx, __shfl_xor(mx, 4));
      mx = fmaxf(mx, __shfl_xor(mx, 8));
      mxloc[mt][rg] = mx;
      float s = 0.f;
#pragma unroll
      for (int tt = 0; tt < 4; ++tt) {
        const float e = __expf(C[mt][tt][rg] - mx);
        C[mt][tt][rg] = e;
        s += e;
      }
      s += __shfl_xor(s, 1);
      s += __shfl_xor(s, 2);
      s += __shfl_xor(s, 4);
      s += __shfl_xor(s, 8);
      if (l15 == 0) {
        const int row = mt * 16 + l4 * 4 + rg;
        red[row][w][0] = mx;
        red[row][w][1] = s;
      }
    }
  }
  __syncthreads();
  if (t < 64) {
    float MX = -3.4e38f;
#pragma unroll
    for (int w8 = 0; w8 < 8; ++w8) MX = fmaxf(MX, red[t][w8][0]);
    float S = 0.f;
#pragma unroll
    for (int w8 = 0; w8 < 8; ++w8) S += red[t][w8][1] * __expf(red[t][w8][0] - MX);
    red2[t][0] = MX;
    red2[t][1] = 1.0f / S;
  }
  __syncthreads();

  // ---- pass 2: normalize p in regs; ssq ----
#pragma unroll
  for (int mt = 0; mt < 4; ++mt) {
#pragma unroll
    for (int rg = 0; rg < 4; ++rg) {
      const int row = mt * 16 + l4 * 4 + rg;
      const float2 g2 = *(const float2*)&red2[row][0];
      const float factor = __expf(mxloc[mt][rg] - g2.x) * g2.y;
      float sq = 0.f;
#pragma unroll
      for (int tt = 0; tt < 4; ++tt) {
        const float p = C[mt][tt][rg] * factor;
        C[mt][tt][rg] = p;
        sq = fmaf(p, p, sq);
      }
      sq += __shfl_xor(sq, 1);
      sq += __shfl_xor(sq, 2);
      sq += __shfl_xor(sq, 4);
      sq += __shfl_xor(sq, 8);
      if (l15 == 0) sq_lds[row][w] = sq;
    }
  }
  __syncthreads();
  if (t < 8) {
    float s8 = 0.f;
#pragma unroll
    for (int rr = 0; rr < 8; ++rr)
#pragma unroll
      for (int w8 = 0; w8 < 8; ++w8) s8 += sq_lds[t * 8 + rr][w8];
    atomicAdd(&ssq[(blk & 15) * 32 + b * 8 + t], s8);
  }

  const int il = w & 3, mh = w >> 2;
  const int mgrp = l >> 3, dl = l & 7;

  // ================= PASS 0: heads 0..3 (Mtiles 0,1) =================
#pragma unroll
  for (int mt = 0; mt < 2; ++mt) {
#pragma unroll
    for (int tt = 0; tt < 4; ++tt) {
#pragma unroll
      for (int rg = 0; rg < 4; ++rg) {
        const int row64 = mt * 16 + l4 * 4 + rg;
        const int hd_ = row64 >> 3, r_ = row64 & 7;
        const int m = w * 64 + tt * 16 + l15;
        P[pswz2(r_ * 4 + hd_, m)] = C[mt][tt][rg];
      }
    }
  }
  __syncthreads();
  {
    float av[8][4];
#pragma unroll
    for (int r = 0; r < 8; ++r)
#pragma unroll
      for (int e = 0; e < 4; ++e) av[r][e] = 0.0f;
    const int mb = mh * 256 + mgrp * 32;
    const int vcol = 256 + il * 32 + dl * 4;
#pragma unroll 2
    for (int mq = 0; mq < 8; ++mq) {
      const int m0 = mb + mq * 4;
      float4 p4[8];
#pragma unroll
      for (int r = 0; r < 8; ++r) p4[r] = *(const float4*)&P[pswz2(r * 4 + il, m0)];
#pragma unroll
      for (int e = 0; e < 4; ++e) {
        const float4 v4 = *(const float4*)&kvb[((b * 512 + m0 + e) * 512) + vcol];
#pragma unroll
        for (int r = 0; r < 8; ++r) {
          const float p = (&p4[r].x)[e];
          av[r][0] = fmaf(p, v4.x, av[r][0]);
          av[r][1] = fmaf(p, v4.y, av[r][1]);
          av[r][2] = fmaf(p, v4.z, av[r][2]);
          av[r][3] = fmaf(p, v4.w, av[r][3]);
        }
      }
    }
#pragma unroll
    for (int r = 0; r < 8; ++r)
#pragma unroll
      for (int e = 0; e < 4; ++e) {
        float v = av[r][e];
        v += __shfl_xor(v, 8);
        v += __shfl_xor(v, 16);
        v += __shfl_xor(v, 32);
        av[r][e] = v;
      }
    __syncthreads();
    if (l < 8) {
#pragma unroll
      for (int r = 0; r < 8; ++r) {
        float4 o;
        o.x = av[r][0]; o.y = av[r][1]; o.z = av[r][2]; o.w = av[r][3];
        *(float4*)&P[w * 256 + r * 32 + dl * 4] = o;
      }
    }
  }
  __syncthreads();
#pragma unroll
  for (int rep = 0; rep < 2; ++rep) {
    const int idx = rep * 512 + t;
    const int il2 = idx >> 8, r2i = (idx >> 5) & 7, dd = idx & 31;
    const float s = P[il2 * 256 + r2i * 32 + dd] + P[(il2 + 4) * 256 + r2i * 32 + dd];
    out_un[((b * 4096) + n0 + r2i) * 256 + il2 * 32 + dd] = s;
  }
  __syncthreads();

  // ================= PASS 1: heads 4..7 (Mtiles 2,3) =================
#pragma unroll
  for (int mt = 0; mt < 2; ++mt) {
#pragma unroll
    for (int tt = 0; tt < 4; ++tt) {
#pragma unroll
      for (int rg = 0; rg < 4; ++rg) {
        const int row64 = (mt + 2) * 16 + l4 * 4 + rg;
        const int hd_ = (row64 >> 3) - 4, r_ = row64 & 7;
        const int m = w * 64 + tt * 16 + l15;
        P[pswz2(r_ * 4 + hd_, m)] = C[mt + 2][tt][rg];
      }
    }
  }
  __syncthreads();
  {
    float av[8][4];
#pragma unroll
    for (int r = 0; r < 8; ++r)
#pragma unroll
      for (int e = 0; e < 4; ++e) av[r][e] = 0.0f;
    const int mb = mh * 256 + mgrp * 32;
    const int vcol = 256 + (4 + il) * 32 + dl * 4;
#pragma unroll 2
    for (int mq = 0; mq < 8; ++mq) {
      const int m0 = mb + mq * 4;
      float4 p4[8];
#pragma unroll
      for (int r = 0; r < 8; ++r) p4[r] = *(const float4*)&P[pswz2(r * 4 + il, m0)];
#pragma unroll
      for (int e = 0; e < 4; ++e) {
        const float4 v4 = *(const float4*)&kvb[((b * 512 + m0 + e) * 512) + vcol];
#pragma unroll
        for (int r = 0; r < 8; ++r) {
          const float p = (&p4[r].x)[e];
          av[r][0] = fmaf(p, v4.x, av[r][0]);
          av[r][1] = fmaf(p, v4.y, av[r][1]);
          av[r][2] = fmaf(p, v4.z, av[r][2]);
          av[r][3] = fmaf(p, v4.w, av[r][3]);
        }
      }
    }
#pragma unroll
    for (int r = 0; r < 8; ++r)
#pragma unroll
      for (int e = 0; e < 4; ++e) {
        float v = av[r][e];
        v += __shfl_xor(v, 8);
        v += __shfl_xor(v, 16);
        v += __shfl_xor(v, 32);
        av[r][e] = v;
      }
    __syncthreads();
    if (l < 8) {
#pragma unroll
      for (int r = 0; r < 8; ++r) {
        float4 o;
        o.x = av[r][0]; o.y = av[r][1]; o.z = av[r][2]; o.w = av[r][3];
        *(float4*)&P[w * 256 + r * 32 + dl * 4] = o;
      }
    }
  }
  __syncthreads();
#pragma unroll
  for (int rep = 0; rep < 2; ++rep) {
    const int idx = rep * 512 + t;
    const int il2 = idx >> 8, r2i = (idx >> 5) & 7, dd = idx & 31;
    const float s = P[il2 * 256 + r2i * 32 + dd] + P[(il2 + 4) * 256 + r2i * 32 + dd];
    out_un[((b * 4096) + n0 + r2i) * 256 + (4 + il2) * 32 + dd] = s;
  }
}

// ---------------------------------------------------------------------------
extern "C" void kernel_launch(void* const* d_in, const int* in_sizes, int n_in,
                              void* d_out, int out_size, void* d_ws, size_t ws_size,
                              hipStream_t stream) {
  const float* x   = (const float*)d_in[0];
  const float* qdww= (const float*)d_in[1];
  const float* qdwb= (const float*)d_in[2];
  const float* bng = (const float*)d_in[3];
  const float* bnb = (const float*)d_in[4];
  const float* bnm = (const float*)d_in[5];
  const float* bnv = (const float*)d_in[6];
  const float* pw  = (const float*)d_in[7];
  const float* pwb = (const float*)d_in[8];
  const float* srw = (const float*)d_in[9];
  const float* srb = (const float*)d_in[10];
  const float* lng = (const float*)d_in[11];
  const float* lnb = (const float*)d_in[12];
  const float* kvw = (const float*)d_in[13];
  const float* tw  = (const float*)d_in[14];
  // d_in[15] = trans_b: softmax-invariant, unused
  const float* pjw = (const float*)d_in[16];
  const float* pjb = (const float*)d_in[17];
  float* out = (float*)d_out;
  float* ws = (float*)d_ws;

  float* qdw   = ws + 0;          // 4,194,304
  float* qbuf  = ws + 4194304;    // 4,194,304
  float* xsln  = ws + 8388608;    //   524,288
  float* kvb   = ws + 8912896;    // 1,048,576
  unsigned short* kthl = (unsigned short*)(ws + 9961472);  // 1,048,576 ushorts (2MB)
  float* wtpw  = ws + 10485760;   //    65,536
  float* wtkv  = ws + 10551296;   //   131,072
  float* wtpj  = ws + 10682368;   //    65,536
  float* sumvp = ws + 10747904;   //     1,024
  float* ssqp  = ws + 10748928;   //       512
  float* rstdp = ws + 10749440;   //        32

  prep_kernel<<<1024, 256, 0, stream>>>(pw, kvw, pjw, wtpw, wtkv, wtpj, ssqp, sumvp);
  dwbn_kernel<<<16384, 256, 0, stream>>>(x, qdww, qdwb, bng, bnb, bnm, bnv, qdw);
  gemm_kernel<0><<<dim3(256, 2), 256, 0, stream>>>(qdw, wtpw, pwb, qbuf, 256, nullptr, nullptr);
  srln_kernel<<<2048, 256, 0, stream>>>(x, srw, srb, lng, lnb, xsln);
  gemm_kernel<0><<<dim3(32, 4), 256, 0, stream>>>(xsln, wtkv, nullptr, kvb, 512, nullptr, nullptr);
  kt_kernel<<<512, 256, 0, stream>>>(kvb, kthl);
  sumv_kernel<<<32, 256, 0, stream>>>(kvb, sumvp);
  attn_kernel<<<2048, 512, 0, stream>>>(qbuf, kthl, kvb, tw, ssqp, out);
  rstd_kernel<<<1, 64, 0, stream>>>(ssqp, rstdp);
  gemm_kernel<1><<<dim3(256, 2), 256, 0, stream>>>(out, wtpj, pjb, out, 256, sumvp, rstdp);
}

// Round 12
// 376.957 us; speedup vs baseline: 1.3031x; 1.3031x over previous
//
#include <hip/hip_runtime.h>
#include <hip/hip_bf16.h>

// Problem constants: B=4, N=4096, C=256, h=8, d=32, M=512, EPS=1e-5
#define SCALE_QK 0.17677669529663687f  // 32^-0.5

typedef __attribute__((ext_vector_type(8))) short bf16x8;
typedef __attribute__((ext_vector_type(4))) float f32x4;

__device__ __forceinline__ unsigned short bf16_rne(float v) {
  const unsigned int b = __float_as_uint(v);
  const unsigned int r = b + 0x7FFFu + ((b >> 16) & 1u);
  return (unsigned short)(r >> 16);
}
__device__ __forceinline__ float bf16_f32(unsigned short h) {
  return __uint_as_float(((unsigned int)h) << 16);
}

// ---------------------------------------------------------------------------
// prep: transpose weights + zero ssq/sumv
// ---------------------------------------------------------------------------
__global__ __launch_bounds__(256) void prep_kernel(
    const float* __restrict__ pw, const float* __restrict__ kvw,
    const float* __restrict__ pjw,
    float* __restrict__ wtpw, float* __restrict__ wtkv, float* __restrict__ wtpj,
    float* __restrict__ ssq, float* __restrict__ sumv) {
  const int g = blockIdx.x * 256 + threadIdx.x;
  if (g < 65536) {
    const int c = g >> 8, o = g & 255;
    wtpw[g] = pw[o * 256 + c];
  } else if (g < 196608) {
    const int g2 = g - 65536;
    const int c = g2 >> 9, o = g2 & 511;
    wtkv[g2] = kvw[o * 256 + c];
  } else {
    const int g3 = g - 196608;
    const int c = g3 >> 8, o = g3 & 255;
    wtpj[g3] = pjw[o * 256 + c];
  }
  if (g < 512) ssq[g] = 0.0f;
  if (g >= 512 && g < 512 + 1024) sumv[g - 512] = 0.0f;
}

// ---------------------------------------------------------------------------
// dwbn v2: depthwise conv3d + BN. Block = (b,z,y) computes a full x-row of 16
// outputs: 9 neighbor-row passes x 18 coalesced loads -> 10 loads/output
// (vs 27). All indices compile-time after unroll; no barriers.
// ---------------------------------------------------------------------------
__global__ __launch_bounds__(256) void dwbn_kernel(
    const float* __restrict__ x, const float* __restrict__ w,
    const float* __restrict__ wb, const float* __restrict__ bg,
    const float* __restrict__ bb, const float* __restrict__ bm,
    const float* __restrict__ bv, float* __restrict__ outq) {
  const int blk = blockIdx.x;  // b*256 + z*16 + y
  const int b = blk >> 8, z = (blk >> 4) & 15, y = blk & 15;
  const int c = threadIdx.x;
  float acc[16];
  const float bias = wb[c];
#pragma unroll
  for (int o = 0; o < 16; ++o) acc[o] = bias;
#pragma unroll
  for (int k0 = 0; k0 < 3; ++k0) {
    const int zz = z + k0 - 1;
    if ((unsigned)zz >= 16u) continue;
#pragma unroll
    for (int k1 = 0; k1 < 3; ++k1) {
      const int yy = y + k1 - 1;
      if ((unsigned)yy >= 16u) continue;
      const float* xrowp = &x[((size_t)(b * 4096) + (zz * 16 + yy) * 16) * 256 + c];
      float xr[18];
      xr[0] = 0.0f;
      xr[17] = 0.0f;
#pragma unroll
      for (int xx = 0; xx < 16; ++xx) xr[xx + 1] = xrowp[xx * 256];
      const float w0 = w[c * 27 + (k0 * 3 + k1) * 3 + 0];
      const float w1 = w[c * 27 + (k0 * 3 + k1) * 3 + 1];
      const float w2 = w[c * 27 + (k0 * 3 + k1) * 3 + 2];
#pragma unroll
      for (int o = 0; o < 16; ++o)
        acc[o] = fmaf(w0, xr[o], fmaf(w1, xr[o + 1], fmaf(w2, xr[o + 2], acc[o])));
    }
  }
  const float sc = bg[c] * rsqrtf(bv[c] + 1e-5f);
  const float bmc = bm[c], bbc = bb[c];
#pragma unroll
  for (int o = 0; o < 16; ++o)
    outq[(size_t)((blk << 4) + o) * 256 + c] = (acc[o] - bmc) * sc + bbc;
}

// ---------------------------------------------------------------------------
// strided depthwise conv3d + LayerNorm -> xsln[B*M, C]
// ---------------------------------------------------------------------------
__global__ __launch_bounds__(256) void srln_kernel(
    const float* __restrict__ x, const float* __restrict__ w,
    const float* __restrict__ wb, const float* __restrict__ lg,
    const float* __restrict__ lb, float* __restrict__ outx) {
  const int blk = blockIdx.x;
  const int b = blk >> 9, m = blk & 511;
  const int o0 = m >> 6, o1 = (m >> 3) & 7, o2 = m & 7;
  const int c = threadIdx.x;
  float acc = wb[c];
#pragma unroll
  for (int k0 = 0; k0 < 3; ++k0) {
    const int z = o0 * 2 + k0 - 1;
    if ((unsigned)z >= 16u) continue;
#pragma unroll
    for (int k1 = 0; k1 < 3; ++k1) {
      const int y = o1 * 2 + k1 - 1;
      if ((unsigned)y >= 16u) continue;
#pragma unroll
      for (int k2 = 0; k2 < 3; ++k2) {
        const int xx = o2 * 2 + k2 - 1;
        if ((unsigned)xx >= 16u) continue;
        acc = fmaf(w[c * 27 + (k0 * 3 + k1) * 3 + k2],
                   x[((b * 4096) + ((z * 16 + y) * 16 + xx)) * 256 + c], acc);
      }
    }
  }
  __shared__ float r1[4], r2[4];
  float s1 = acc, s2 = acc * acc;
#pragma unroll
  for (int off = 32; off >= 1; off >>= 1) {
    s1 += __shfl_xor(s1, off);
    s2 += __shfl_xor(s2, off);
  }
  const int t = threadIdx.x;
  if ((t & 63) == 0) { r1[t >> 6] = s1; r2[t >> 6] = s2; }
  __syncthreads();
  const float mu = (r1[0] + r1[1] + r1[2] + r1[3]) * (1.0f / 256.0f);
  const float ms = (r2[0] + r2[1] + r2[2] + r2[3]) * (1.0f / 256.0f);
  const float rs = rsqrtf(ms - mu * mu + 1e-5f);
  outx[blk * 256 + c] = (acc - mu) * rs * lg[c] + lb[c];
}

// ---------------------------------------------------------------------------
// GEMM v2: 64 rows x 128 cols per block. MODE 1: deferred instance-norm on A.
// ---------------------------------------------------------------------------
template <int MODE>
__global__ __launch_bounds__(256) void gemm_kernel(
    const float* __restrict__ A, const float* __restrict__ Wt,
    const float* __restrict__ bias, float* __restrict__ Out, const int ldW,
    const float* __restrict__ sumv, const float* __restrict__ rstd) {
  __shared__ float a_t[32][68];
  __shared__ float w_s[32][132];
  const int t = threadIdx.x;
  const int r0 = blockIdx.x * 64;
  const int c0 = blockIdx.y * 128;
  const int rt = t & 15, ct = t >> 4;
  const int bidx = r0 >> 12;
  const float invM = 1.0f / 512.0f;
  float acc[4][8];
#pragma unroll
  for (int rr = 0; rr < 4; ++rr)
#pragma unroll
    for (int cc = 0; cc < 8; ++cc) acc[rr][cc] = 0.0f;

  for (int k0 = 0; k0 < 256; k0 += 32) {
    {
      const int kk = t & 31;
      int rl = t >> 5;
#pragma unroll
      for (int p = 0; p < 8; ++p, rl += 8) {
        float v = A[(r0 + rl) * 256 + k0 + kk];
        if (MODE == 1) {
          const int kg = k0 + kk;
          v = (v - invM * sumv[bidx * 256 + kg]) * rstd[bidx * 8 + (kg >> 5)];
        }
        a_t[kk][rl] = v;
      }
    }
    {
      const int cq = (t & 31) * 4;
      int kk = t >> 5;
#pragma unroll
      for (int p = 0; p < 4; ++p, kk += 8) {
        const float4 v = *(const float4*)&Wt[(k0 + kk) * ldW + c0 + cq];
        *(float4*)&w_s[kk][cq] = v;
      }
    }
    __syncthreads();
#pragma unroll
    for (int kk = 0; kk < 32; ++kk) {
      const float4 a4 = *(const float4*)&a_t[kk][rt * 4];
      const float av[4] = {a4.x, a4.y, a4.z, a4.w};
      float4 w4[2];
#pragma unroll
      for (int q = 0; q < 2; ++q) w4[q] = *(const float4*)&w_s[kk][ct * 8 + q * 4];
#pragma unroll
      for (int rr = 0; rr < 4; ++rr) {
#pragma unroll
        for (int q = 0; q < 2; ++q) {
          acc[rr][q * 4 + 0] = fmaf(av[rr], w4[q].x, acc[rr][q * 4 + 0]);
          acc[rr][q * 4 + 1] = fmaf(av[rr], w4[q].y, acc[rr][q * 4 + 1]);
          acc[rr][q * 4 + 2] = fmaf(av[rr], w4[q].z, acc[rr][q * 4 + 2]);
          acc[rr][q * 4 + 3] = fmaf(av[rr], w4[q].w, acc[rr][q * 4 + 3]);
        }
      }
    }
    __syncthreads();
  }
#pragma unroll
  for (int rr = 0; rr < 4; ++rr) {
    const int row = r0 + rt * 4 + rr;
#pragma unroll
    for (int q = 0; q < 2; ++q) {
      const int cc = c0 + ct * 8 + q * 4;
      float4 o;
      o.x = acc[rr][q * 4 + 0];
      o.y = acc[rr][q * 4 + 1];
      o.z = acc[rr][q * 4 + 2];
      o.w = acc[rr][q * 4 + 3];
      if (bias != nullptr) {
        o.x += bias[cc + 0]; o.y += bias[cc + 1];
        o.z += bias[cc + 2]; o.w += bias[cc + 3];
      }
      *(float4*)&Out[row * ldW + cc] = o;
    }
  }
}

// ---------------------------------------------------------------------------
// kt v2: K^T -> bf16 hi/lo packed in MFMA B-frag order:
// kthl[b][kt8=k>>3][m][s][e=k&7] ushort; b128-loadable per lane.
// ---------------------------------------------------------------------------
__global__ __launch_bounds__(256) void kt_kernel(const float* __restrict__ kvb,
                                                 unsigned short* __restrict__ kthl) {
  __shared__ float tile[32][33];
  const int blk = blockIdx.x;  // b(4) x mt(16) x k8(8)
  const int b = blk >> 7, mt = (blk >> 3) & 15, k8 = blk & 7;
  const int m0 = mt * 32, k0 = k8 * 32;
  const int t = threadIdx.x;
  {
    const int ml = t >> 3, kl = (t & 7) * 4;
    const float4 v = *(const float4*)&kvb[((b * 512 + m0 + ml) * 512) + k0 + kl];
    tile[ml][kl + 0] = v.x; tile[ml][kl + 1] = v.y;
    tile[ml][kl + 2] = v.z; tile[ml][kl + 3] = v.w;
  }
  __syncthreads();
  {
    const int s = t >> 7, kt8l = (t >> 5) & 3, mloc = t & 31;
    unsigned int pk[4];
#pragma unroll
    for (int ep = 0; ep < 4; ++ep) {
      unsigned short h0, h1;
      {
        const float v = tile[mloc][kt8l * 8 + ep * 2];
        const unsigned short hi = bf16_rne(v);
        h0 = (s == 0) ? hi : bf16_rne(v - bf16_f32(hi));
      }
      {
        const float v = tile[mloc][kt8l * 8 + ep * 2 + 1];
        const unsigned short hi = bf16_rne(v);
        h1 = (s == 0) ? hi : bf16_rne(v - bf16_f32(hi));
      }
      pk[ep] = (unsigned int)h0 | ((unsigned int)h1 << 16);
    }
    const int kt8 = k8 * 4 + kt8l;
    uint4 u;
    u.x = pk[0]; u.y = pk[1]; u.z = pk[2]; u.w = pk[3];
    *(uint4*)&kthl[((((size_t)b * 32 + kt8) * 512 + (m0 + mloc)) * 2 + s) * 8] = u;
  }
}

// ---------------------------------------------------------------------------
// sumv[b][c] = sum_m v[b][m][c]
// ---------------------------------------------------------------------------
__global__ __launch_bounds__(256) void sumv_kernel(const float* __restrict__ kvb,
                                                   float* __restrict__ sumv) {
  const int blk = blockIdx.x;
  const int b = blk >> 3, grp = blk & 7;
  const int c = threadIdx.x;
  float s = 0.0f;
  for (int mm = 0; mm < 64; ++mm) {
    const int m = grp * 64 + mm;
    s += kvb[((b * 512 + m) * 512) + 256 + c];
  }
  atomicAdd(&sumv[b * 256 + c], s);
}

__global__ void rstd_kernel(const float* __restrict__ ssq, float* __restrict__ rstd) {
  const int t = threadIdx.x;
  if (t < 32) {
    float s = 0.0f;
#pragma unroll
    for (int sp = 0; sp < 16; ++sp) s += ssq[sp * 32 + t];
    const float e2 = s * (1.0f / (4096.0f * 512.0f));
    const float invM = 1.0f / 512.0f;
    rstd[t] = rsqrtf(e2 - invM * invM + 1e-5f);
  }
}

// ---------------------------------------------------------------------------
// Fused attention v10: v9 (QK+mix as split-bf16 MFMA GEMM) with
// (a) conflict-free p swizzle: key = (q>>3)&7 (spreads PV's mgrp reads)
//     XOR ((row>>2)&1)<<2 (spreads the C-frag scatter's l4 row groups);
// (b) A-staging packed as uint2 stores (4 ushorts) instead of scalars.
// PV fp32 path unchanged (verified).
// ---------------------------------------------------------------------------
__device__ __forceinline__ int pswz3(int row, int m) {
  const int q = m >> 2;
  const int qs = q ^ ((q >> 3) & 7) ^ (((row >> 2) & 1) << 2);
  return row * 512 + (qs << 2) + (m & 3);
}

__global__ __launch_bounds__(512, 4) void attn_kernel(
    const float* __restrict__ qb, const unsigned short* __restrict__ kthl,
    const float* __restrict__ kvb, const float* __restrict__ tw,
    float* __restrict__ ssq, float* __restrict__ out_un) {
  __shared__ float P[16384];       // 64KB: A-frags (QK) -> p / partials (PV)
  __shared__ float red[64][8][2];  // wave-local max/expsum
  __shared__ float red2[64][2];    // global MX, 1/S per row
  __shared__ float sq_lds[64][8];
  const int t = threadIdx.x, blk = blockIdx.x;
  const int b = blk >> 9, n0 = (blk & 511) << 3;
  const int w = t >> 6, l = t & 63;
  const int l15 = l & 15, l4 = l >> 4;
  unsigned short* Au = (unsigned short*)P;  // [mt4][kt8][s2][lane64][e8]

  // ---- stage A (q * W * scale, hi/lo) into frag layout; uint2-packed ----
  {
    const int r = t >> 6, c4 = (t & 63) * 4;
    const float4 q4 = *(const float4*)&qb[((b * 4096 + n0 + r) * 256) + c4];
    const float qv[4] = {q4.x, q4.y, q4.z, q4.w};
    const int kt = c4 >> 5;
    const int e0 = c4 & 7;                       // 0 or 4
    const int lanehi = ((c4 & 31) >> 3) << 4;    // 0 or 16
#pragma unroll
    for (int i = 0; i < 8; ++i) {
      const float wij = tw[i * 8 + kt] * SCALE_QK;
      const int mt = i >> 1;
      const int lane = ((i & 1) * 8 + r) | lanehi;
      unsigned int ph[2], pl[2];
#pragma unroll
      for (int pp = 0; pp < 2; ++pp) {
        const float v0 = qv[pp * 2 + 0] * wij;
        const float v1 = qv[pp * 2 + 1] * wij;
        const unsigned short h0 = bf16_rne(v0);
        const unsigned short h1 = bf16_rne(v1);
        const unsigned short lo0 = bf16_rne(v0 - bf16_f32(h0));
        const unsigned short lo1 = bf16_rne(v1 - bf16_f32(h1));
        ph[pp] = (unsigned int)h0 | ((unsigned int)h1 << 16);
        pl[pp] = (unsigned int)lo0 | ((unsigned int)lo1 << 16);
      }
      const int base = (((mt * 8 + kt) * 2) * 64 + lane) * 8 + e0;
      uint2 uh; uh.x = ph[0]; uh.y = ph[1];
      uint2 ul; ul.x = pl[0]; ul.y = pl[1];
      *(uint2*)&Au[base] = uh;
      *(uint2*)&Au[base + 512] = ul;  // s=1 plane
    }
  }
  __syncthreads();

  // ---- QK mfma: wave w owns m in [w*64, w*64+64) (4 tiles of 16) ----
  f32x4 C[4][4];  // [mt][t]
#pragma unroll
  for (int mt = 0; mt < 4; ++mt)
#pragma unroll
    for (int tt = 0; tt < 4; ++tt) C[mt][tt] = (f32x4){0.f, 0.f, 0.f, 0.f};

#pragma unroll
  for (int kt = 0; kt < 8; ++kt) {
#pragma unroll
    for (int th = 0; th < 2; ++th) {
      bf16x8 Bh[2], Bl[2];
#pragma unroll
      for (int tp = 0; tp < 2; ++tp) {
        const int m = w * 64 + (th * 2 + tp) * 16 + l15;
        const size_t bi = ((((size_t)b * 32 + kt * 4 + l4) * 512 + m) * 2) * 8;
        Bh[tp] = *(const bf16x8*)&kthl[bi];
        Bl[tp] = *(const bf16x8*)&kthl[bi + 8];
      }
#pragma unroll
      for (int mt = 0; mt < 4; ++mt) {
        const int ab = (((mt * 8 + kt) * 2) * 64 + l) * 8;
        const bf16x8 Ah = *(const bf16x8*)&Au[ab];
        const bf16x8 Al = *(const bf16x8*)&Au[ab + 512];
#pragma unroll
        for (int tp = 0; tp < 2; ++tp) {
          const int ti = th * 2 + tp;
          C[mt][ti] = __builtin_amdgcn_mfma_f32_16x16x32_bf16(Ah, Bh[tp], C[mt][ti], 0, 0, 0);
          C[mt][ti] = __builtin_amdgcn_mfma_f32_16x16x32_bf16(Ah, Bl[tp], C[mt][ti], 0, 0, 0);
          C[mt][ti] = __builtin_amdgcn_mfma_f32_16x16x32_bf16(Al, Bh[tp], C[mt][ti], 0, 0, 0);
        }
      }
    }
  }

  // ---- softmax pass 1 (wave-local, 16-lane row groups) ----
  float mxloc[4][4];
#pragma unroll
  for (int mt = 0; mt < 4; ++mt) {
#pragma unroll
    for (int rg = 0; rg < 4; ++rg) {
      float mx = fmaxf(fmaxf(C[mt][0][rg], C[mt][1][rg]),
                       fmaxf(C[mt][2][rg], C[mt][3][rg]));
      mx = fmaxf(mx, __shfl_xor(mx, 1));
      mx = fmaxf(mx, __shfl_xor(mx, 2));
      mx = fmaxf(mx, __shfl_xor(mx, 4));
      mx = fmaxf(mx, __shfl_xor(mx, 8));
      mxloc[mt][rg] = mx;
      float s = 0.f;
#pragma unroll
      for (int tt = 0; tt < 4; ++tt) {
        const float e = __expf(C[mt][tt][rg] - mx);
        C[mt][tt][rg] = e;
        s += e;
      }
      s += __shfl_xor(s, 1);
      s += __shfl_xor(s, 2);
      s += __shfl_xor(s, 4);
      s += __shfl_xor(s, 8);
      if (l15 == 0) {
        const int row = mt * 16 + l4 * 4 + rg;
        red[row][w][0] = mx;
        red[row][w][1] = s;
      }
    }
  }
  __syncthreads();
  if (t < 64) {
    float MX = -3.4e38f;
#pragma unroll
    for (int w8 = 0; w8 < 8; ++w8) MX = fmaxf(MX, red[t][w8][0]);
    float S = 0.f;
#pragma unroll
    for (int w8 = 0; w8 < 8; ++w8) S += red[t][w8][1] * __expf(red[t][w8][0] - MX);
    red2[t][0] = MX;
    red2[t][1] = 1.0f / S;
  }
  __syncthreads();

  // ---- pass 2: normalize p in regs; ssq ----
#pragma unroll
  for (int mt = 0; mt < 4; ++mt) {
#pragma unroll
    for (int rg = 0; rg < 4; ++rg) {
      const int row = mt * 16 + l4 * 4 + rg;
      const float2 g2 = *(const float2*)&red2[row][0];
      const float factor = __expf(mxloc[mt][rg] - g2.x) * g2.y;
      float sq = 0.f;
#pragma unroll
      for (int tt = 0; tt < 4; ++tt) {
        const float p = C[mt][tt][rg] * factor;
        C[mt][tt][rg] = p;
        sq = fmaf(p, p, sq);
      }
      sq += __shfl_xor(sq, 1);
      sq += __shfl_xor(sq, 2);
      sq += __shfl_xor(sq, 4);
      sq += __shfl_xor(sq, 8);
      if (l15 == 0) sq_lds[row][w] = sq;
    }
  }
  __syncthreads();
  if (t < 8) {
    float s8 = 0.f;
#pragma unroll
    for (int rr = 0; rr < 8; ++rr)
#pragma unroll
      for (int w8 = 0; w8 < 8; ++w8) s8 += sq_lds[t * 8 + rr][w8];
    atomicAdd(&ssq[(blk & 15) * 32 + b * 8 + t], s8);
  }

  const int il = w & 3, mh = w >> 2;
  const int mgrp = l >> 3, dl = l & 7;

  // ================= PASS 0: heads 0..3 (Mtiles 0,1) =================
#pragma unroll
  for (int mt = 0; mt < 2; ++mt) {
#pragma unroll
    for (int tt = 0; tt < 4; ++tt) {
#pragma unroll
      for (int rg = 0; rg < 4; ++rg) {
        const int rowp = mt * 16 + l4 * 4 + rg;  // row64 0..31 = hd*8+r
        const int m = w * 64 + tt * 16 + l15;
        P[pswz3(rowp, m)] = C[mt][tt][rg];
      }
    }
  }
  __syncthreads();
  {
    float av[8][4];
#pragma unroll
    for (int r = 0; r < 8; ++r)
#pragma unroll
      for (int e = 0; e < 4; ++e) av[r][e] = 0.0f;
    const int mb = mh * 256 + mgrp * 32;
    const int vcol = 256 + il * 32 + dl * 4;
#pragma unroll 2
    for (int mq = 0; mq < 8; ++mq) {
      const int m0 = mb + mq * 4;
      float4 p4[8];
#pragma unroll
      for (int r = 0; r < 8; ++r) p4[r] = *(const float4*)&P[pswz3(il * 8 + r, m0)];
#pragma unroll
      for (int e = 0; e < 4; ++e) {
        const float4 v4 = *(const float4*)&kvb[((b * 512 + m0 + e) * 512) + vcol];
#pragma unroll
        for (int r = 0; r < 8; ++r) {
          const float p = (&p4[r].x)[e];
          av[r][0] = fmaf(p, v4.x, av[r][0]);
          av[r][1] = fmaf(p, v4.y, av[r][1]);
          av[r][2] = fmaf(p, v4.z, av[r][2]);
          av[r][3] = fmaf(p, v4.w, av[r][3]);
        }
      }
    }
#pragma unroll
    for (int r = 0; r < 8; ++r)
#pragma unroll
      for (int e = 0; e < 4; ++e) {
        float v = av[r][e];
        v += __shfl_xor(v, 8);
        v += __shfl_xor(v, 16);
        v += __shfl_xor(v, 32);
        av[r][e] = v;
      }
    __syncthreads();
    if (l < 8) {
#pragma unroll
      for (int r = 0; r < 8; ++r) {
        float4 o;
        o.x = av[r][0]; o.y = av[r][1]; o.z = av[r][2]; o.w = av[r][3];
        *(float4*)&P[w * 256 + r * 32 + dl * 4] = o;
      }
    }
  }
  __syncthreads();
#pragma unroll
  for (int rep = 0; rep < 2; ++rep) {
    const int idx = rep * 512 + t;
    const int il2 = idx >> 8, r2i = (idx >> 5) & 7, dd = idx & 31;
    const float s = P[il2 * 256 + r2i * 32 + dd] + P[(il2 + 4) * 256 + r2i * 32 + dd];
    out_un[((b * 4096) + n0 + r2i) * 256 + il2 * 32 + dd] = s;
  }
  __syncthreads();

  // ================= PASS 1: heads 4..7 (Mtiles 2,3) =================
#pragma unroll
  for (int mt = 0; mt < 2; ++mt) {
#pragma unroll
    for (int tt = 0; tt < 4; ++tt) {
#pragma unroll
      for (int rg = 0; rg < 4; ++rg) {
        const int rowp = mt * 16 + l4 * 4 + rg;  // local 0..31 (heads 4..7)
        const int m = w * 64 + tt * 16 + l15;
        P[pswz3(rowp, m)] = C[mt + 2][tt][rg];
      }
    }
  }
  __syncthreads();
  {
    float av[8][4];
#pragma unroll
    for (int r = 0; r < 8; ++r)
#pragma unroll
      for (int e = 0; e < 4; ++e) av[r][e] = 0.0f;
    const int mb = mh * 256 + mgrp * 32;
    const int vcol = 256 + (4 + il) * 32 + dl * 4;
#pragma unroll 2
    for (int mq = 0; mq < 8; ++mq) {
      const int m0 = mb + mq * 4;
      float4 p4[8];
#pragma unroll
      for (int r = 0; r < 8; ++r) p4[r] = *(const float4*)&P[pswz3(il * 8 + r, m0)];
#pragma unroll
      for (int e = 0; e < 4; ++e) {
        const float4 v4 = *(const float4*)&kvb[((b * 512 + m0 + e) * 512) + vcol];
#pragma unroll
        for (int r = 0; r < 8; ++r) {
          const float p = (&p4[r].x)[e];
          av[r][0] = fmaf(p, v4.x, av[r][0]);
          av[r][1] = fmaf(p, v4.y, av[r][1]);
          av[r][2] = fmaf(p, v4.z, av[r][2]);
          av[r][3] = fmaf(p, v4.w, av[r][3]);
        }
      }
    }
#pragma unroll
    for (int r = 0; r < 8; ++r)
#pragma unroll
      for (int e = 0; e < 4; ++e) {
        float v = av[r][e];
        v += __shfl_xor(v, 8);
        v += __shfl_xor(v, 16);
        v += __shfl_xor(v, 32);
        av[r][e] = v;
      }
    __syncthreads();
    if (l < 8) {
#pragma unroll
      for (int r = 0; r < 8; ++r) {
        float4 o;
        o.x = av[r][0]; o.y = av[r][1]; o.z = av[r][2]; o.w = av[r][3];
        *(float4*)&P[w * 256 + r * 32 + dl * 4] = o;
      }
    }
  }
  __syncthreads();
#pragma unroll
  for (int rep = 0; rep < 2; ++rep) {
    const int idx = rep * 512 + t;
    const int il2 = idx >> 8, r2i = (idx >> 5) & 7, dd = idx & 31;
    const float s = P[il2 * 256 + r2i * 32 + dd] + P[(il2 + 4) * 256 + r2i * 32 + dd];
    out_un[((b * 4096) + n0 + r2i) * 256 + (4 + il2) * 32 + dd] = s;
  }
}

// ---------------------------------------------------------------------------
extern "C" void kernel_launch(void* const* d_in, const int* in_sizes, int n_in,
                              void* d_out, int out_size, void* d_ws, size_t ws_size,
                              hipStream_t stream) {
  const float* x   = (const float*)d_in[0];
  const float* qdww= (const float*)d_in[1];
  const float* qdwb= (const float*)d_in[2];
  const float* bng = (const float*)d_in[3];
  const float* bnb = (const float*)d_in[4];
  const float* bnm = (const float*)d_in[5];
  const float* bnv = (const float*)d_in[6];
  const float* pw  = (const float*)d_in[7];
  const float* pwb = (const float*)d_in[8];
  const float* srw = (const float*)d_in[9];
  const float* srb = (const float*)d_in[10];
  const float* lng = (const float*)d_in[11];
  const float* lnb = (const float*)d_in[12];
  const float* kvw = (const float*)d_in[13];
  const float* tw  = (const float*)d_in[14];
  // d_in[15] = trans_b: softmax-invariant, unused
  const float* pjw = (const float*)d_in[16];
  const float* pjb = (const float*)d_in[17];
  float* out = (float*)d_out;
  float* ws = (float*)d_ws;

  float* qdw   = ws + 0;          // 4,194,304
  float* qbuf  = ws + 4194304;    // 4,194,304
  float* xsln  = ws + 8388608;    //   524,288
  float* kvb   = ws + 8912896;    // 1,048,576
  unsigned short* kthl = (unsigned short*)(ws + 9961472);  // 2MB
  float* wtpw  = ws + 10485760;   //    65,536
  float* wtkv  = ws + 10551296;   //   131,072
  float* wtpj  = ws + 10682368;   //    65,536
  float* sumvp = ws + 10747904;   //     1,024
  float* ssqp  = ws + 10748928;   //       512
  float* rstdp = ws + 10749440;   //        32

  prep_kernel<<<1024, 256, 0, stream>>>(pw, kvw, pjw, wtpw, wtkv, wtpj, ssqp, sumvp);
  dwbn_kernel<<<1024, 256, 0, stream>>>(x, qdww, qdwb, bng, bnb, bnm, bnv, qdw);
  gemm_kernel<0><<<dim3(256, 2), 256, 0, stream>>>(qdw, wtpw, pwb, qbuf, 256, nullptr, nullptr);
  srln_kernel<<<2048, 256, 0, stream>>>(x, srw, srb, lng, lnb, xsln);
  gemm_kernel<0><<<dim3(32, 4), 256, 0, stream>>>(xsln, wtkv, nullptr, kvb, 512, nullptr, nullptr);
  kt_kernel<<<512, 256, 0, stream>>>(kvb, kthl);
  sumv_kernel<<<32, 256, 0, stream>>>(kvb, sumvp);
  attn_kernel<<<2048, 512, 0, stream>>>(qbuf, kthl, kvb, tw, ssqp, out);
  rstd_kernel<<<1, 64, 0, stream>>>(ssqp, rstdp);
  gemm_kernel<1><<<dim3(256, 2), 256, 0, stream>>>(out, wtpj, pjb, out, 256, sumvp, rstdp);
}